// Round 1
// 396.558 us; speedup vs baseline: 1.0496x; 1.0496x over previous
//
#include <hip/hip_runtime.h>

#define S_LEN 2048
#define D_DIM 128
#define BQ 64
#define BK 32
#define NITER (S_LEN / BK)   // 64

typedef float f32x4 __attribute__((ext_vector_type(4)));
typedef short s16x8 __attribute__((ext_vector_type(8)));
typedef short s16x4 __attribute__((ext_vector_type(4)));
typedef unsigned int u32;

#if __has_builtin(__builtin_amdgcn_exp2f)
#define EXP2(x) __builtin_amdgcn_exp2f(x)
#else
#define EXP2(x) exp2f(x)
#endif

// pack two floats' bf16 into one u32: x0 in lower 16, x1 in upper 16
__device__ __forceinline__ u32 pack_trunc(float x0, float x1) {
    return __builtin_amdgcn_perm(__float_as_uint(x1), __float_as_uint(x0), 0x07060302u);
}
__device__ __forceinline__ u32 pack_rne(float x0, float x1) {
    return __builtin_amdgcn_perm(__float_as_uint(x1) + 0x8000u,
                                 __float_as_uint(x0) + 0x8000u, 0x07060302u);
}

#define GLOAD16(g, l) \
    __builtin_amdgcn_global_load_lds((const __attribute__((address_space(1))) u32*)(g), \
                                     (__attribute__((address_space(3))) u32*)(l), 16, 0, 0)

// K=16 bf16 MFMA: A/B frag = 4 bf16 (lane: elem k = quad*4 + j), C/D = f32x4.
#if __has_builtin(__builtin_amdgcn_mfma_f32_16x16x16bf16_1k)
__device__ __forceinline__ f32x4 MFMA16(s16x4 a, s16x4 b, f32x4 c) {
    return __builtin_amdgcn_mfma_f32_16x16x16bf16_1k(a, b, c, 0, 0, 0);
}
#else
__device__ __forceinline__ f32x4 MFMA16(s16x4 a, s16x4 b, f32x4 c) {
    asm("v_mfma_f32_16x16x16_bf16 %0, %1, %2, %0" : "+v"(c) : "v"(a), "v"(b));
    return c;
}
#endif

// ---------------- pre-pass: K -> hi/lo bf16, tiled + XOR-swizzled 16B units ----------------
// Kc layout: [bh][kt][r=0..31][u'=0..31][8 ushorts]; u = 2c (hi) / 2c+1 (lo); u' = u ^ (r&7).
__global__ void prep_k(const float* __restrict__ K, unsigned short* __restrict__ Kc) {
    const int t  = blockIdx.x * 256 + threadIdx.x;   // 2^20 threads
    const int c  = t & 15;
    const int s  = (t >> 4) & (S_LEN - 1);
    const int bh = t >> 15;
    const float* src = K + ((size_t)bh * S_LEN + s) * D_DIM + c * 8;
    const float4 a = *(const float4*)src;
    const float4 b = *(const float4*)(src + 4);
    const float x[8] = {a.x,a.y,a.z,a.w,b.x,b.y,b.z,b.w};
    u32 h[4], l[4];
    #pragma unroll
    for (int i = 0; i < 4; ++i) {
        const float x0 = x[2*i], x1 = x[2*i+1];
        h[i] = pack_trunc(x0, x1);
        const float r0 = x0 - __uint_as_float(__float_as_uint(x0) & 0xFFFF0000u);
        const float r1 = x1 - __uint_as_float(__float_as_uint(x1) & 0xFFFF0000u);
        l[i] = pack_trunc(r0, r1);
    }
    const int kt = s >> 5, r = s & 31, rl = r & 7;
    unsigned short* base = Kc + ((((size_t)bh * NITER + kt) * 32 + r) << 8);
    *(uint4*)(base + (((2*c)     ^ rl) << 3)) = make_uint4(h[0],h[1],h[2],h[3]);
    *(uint4*)(base + (((2*c + 1) ^ rl) << 3)) = make_uint4(l[0],l[1],l[2],l[3]);
}

// ---------------- pre-pass: V -> transposed bf16 tiles Vt[bh][kt][d][kk] ----------------
// 16B units within each 64B row XOR-swizzled: physical unit = logical ^ ((d>>1)&3).
__global__ void prep_v(const float* __restrict__ V, unsigned short* __restrict__ Vt) {
    const int t  = blockIdx.x * 256 + threadIdx.x;   // 2^18 threads
    const int d  = t & 127;
    const int kt = (t >> 7) & (NITER - 1);
    const int bh = t >> 13;
    const float* src = V + (((size_t)bh * NITER + kt) * BK) * D_DIM + d;
    u32 wv[16];
    #pragma unroll
    for (int i = 0; i < 16; ++i)
        wv[i] = pack_rne(src[(2*i) * D_DIM], src[(2*i+1) * D_DIM]);
    unsigned short* dst = Vt + ((((size_t)bh * NITER + kt) * D_DIM + d) << 5);
    const int vs = (d >> 1) & 3;
    #pragma unroll
    for (int i = 0; i < 4; ++i)
        *(uint4*)(dst + ((i ^ vs) << 3)) = make_uint4(wv[4*i],wv[4*i+1],wv[4*i+2],wv[4*i+3]);
}

// ---------------- hot kernel: swapped-operand QK/PV, lane-local softmax ----------------
__global__ __launch_bounds__(256, 3)
void attn_fused(const float* __restrict__ Q, const unsigned short* __restrict__ Kc,
                const unsigned short* __restrict__ Vt, const float* __restrict__ SF,
                const int* __restrict__ DP, float* __restrict__ OUT)
{
    __shared__ __align__(16) unsigned short sK[2][32 * 256];    // 2 x 16 KB
    __shared__ __align__(16) unsigned short sVt[2][128 * 32];   // 2 x 8 KB

    const int bh   = blockIdx.y;
    const int q0   = blockIdx.x * BQ;
    const int tid  = threadIdx.x;
    const int w    = tid >> 6;
    const int lane = tid & 63;
    const int quad = lane >> 4;
    const int lr   = lane & 15;
    const int rl   = lr & 7;

    const size_t bh_off = (size_t)bh * S_LEN * D_DIM;
    const float LOG2E = 1.4426950408889634f;

    // ---- Q fragments, hi/lo bf16 split (lane holds Q[q=lr][d = d0*32 + quad*8 + j]) ----
    s16x8 qhi[4], qlo[4];
    const int qrow = q0 + w * 16 + lr;
    {
        const float* qr = Q + bh_off + (size_t)qrow * D_DIM + quad * 8;
        #pragma unroll
        for (int d0 = 0; d0 < 4; ++d0) {
            const float4 u0 = *(const float4*)(qr + d0 * 32);
            const float4 u1 = *(const float4*)(qr + d0 * 32 + 4);
            const float x[8] = {u0.x,u0.y,u0.z,u0.w,u1.x,u1.y,u1.z,u1.w};
            union { u32 w4[4]; s16x8 v; } H, L;
            #pragma unroll
            for (int i = 0; i < 4; ++i) {
                const float x0 = x[2*i], x1 = x[2*i+1];
                H.w4[i] = pack_trunc(x0, x1);
                const float r0 = x0 - __uint_as_float(__float_as_uint(x0) & 0xFFFF0000u);
                const float r1 = x1 - __uint_as_float(__float_as_uint(x1) & 0xFFFF0000u);
                L.w4[i] = pack_trunc(r0, r1);
            }
            qhi[d0] = H.v; qlo[d0] = L.v;
        }
    }

    // O^T accumulator: Oacc[dt][r] = O[q=lr][d = dt*16 + quad*4 + r]
    f32x4 Oacc[8] = {};
    float mrow = -INFINITY, lrow = 0.f;

    const unsigned short* KtBase = Kc + (((size_t)bh * NITER) << 13);
    const unsigned short* VtBase = Vt + (((size_t)bh * NITER) << 12);

    // lane-constant swizzled V read offsets (bytes within a 64B Vt row)
    const int vsl  = (lr >> 1) & 3;
    const int off0 = ((((quad >> 1))     ^ vsl) << 4) + (quad & 1) * 8;   // nt=0
    const int off1 = (((2 + (quad >> 1)) ^ vsl) << 4) + (quad & 1) * 8;   // nt=1

    // ---- prologue: DMA tile 0 -> buf 0; SF tile 0 -> regs ----
    #pragma unroll
    for (int i = 0; i < 4; ++i)
        GLOAD16(KtBase + (w * 4 + i) * 512 + lane * 8, &sK[0][(w * 4 + i) * 512]);
    #pragma unroll
    for (int i = 0; i < 2; ++i)
        GLOAD16(VtBase + (w * 2 + i) * 512 + lane * 8, &sVt[0][(w * 2 + i) * 512]);

    // SF: lane needs cols kt*32 + nt*16 + quad*4 + 0..3 of its own row -> float4 loads
    const float* sfq = SF + (size_t)qrow * S_LEN + quad * 4;
    f32x4 sf0, sf1;
    {
        const f32x4 l2e = {LOG2E, LOG2E, LOG2E, LOG2E};
        sf0 = *(const f32x4*)(sfq) * l2e;
        sf1 = *(const f32x4*)(sfq + 16) * l2e;
    }

    for (int kt = 0; kt < NITER; ++kt) {
        const int p = kt & 1;
        // Publishes buf[p] (vmcnt(0) drain: its DMA was issued a full iteration
        // ago). Also guarantees everyone is done reading buf[1-p].
        __syncthreads();

        // ---- prefetch tile kt+1 into buf[1-p]; SF(kt+1) into regs ----
        f32x4 nf0, nf1;
        const bool more = (kt + 1 < NITER);
        if (more) {
            const unsigned short* Kn = KtBase + ((size_t)(kt + 1) << 13);
            const unsigned short* Vn = VtBase + ((size_t)(kt + 1) << 12);
            #pragma unroll
            for (int i = 0; i < 4; ++i)
                GLOAD16(Kn + (w * 4 + i) * 512 + lane * 8, &sK[1 - p][(w * 4 + i) * 512]);
            #pragma unroll
            for (int i = 0; i < 2; ++i)
                GLOAD16(Vn + (w * 2 + i) * 512 + lane * 8, &sVt[1 - p][(w * 2 + i) * 512]);
            const f32x4 l2e = {LOG2E, LOG2E, LOG2E, LOG2E};
            nf0 = *(const f32x4*)(sfq + (kt + 1) * 32) * l2e;
            nf1 = *(const f32x4*)(sfq + (kt + 1) * 32 + 16) * l2e;
        }

        // ---- QK^T, swapped operands: acc[nt][r] = S[q=lr][k = nt*16 + quad*4 + r] ----
        const unsigned short* sKp = sK[p];
        f32x4 acc[2] = {};
        #pragma unroll
        for (int nt = 0; nt < 2; ++nt) {
            const unsigned short* rowp = sKp + (nt * 16 + lr) * 256;
            #pragma unroll
            for (int d0 = 0; d0 < 4; ++d0) {
                const int uh = (8 * d0 + 2 * quad) ^ rl;
                const s16x8 kh8 = *(const s16x8*)(rowp + (uh << 3));
                const s16x8 kl8 = *(const s16x8*)(rowp + ((uh ^ 1) << 3));
                acc[nt] = __builtin_amdgcn_mfma_f32_16x16x32_bf16(kh8, qlo[d0], acc[nt], 0, 0, 0);
                acc[nt] = __builtin_amdgcn_mfma_f32_16x16x32_bf16(kl8, qhi[d0], acc[nt], 0, 0, 0);
                acc[nt] = __builtin_amdgcn_mfma_f32_16x16x32_bf16(kh8, qhi[d0], acc[nt], 0, 0, 0);
            }
        }

        // ---- online softmax (base-2), lane-local row + 2 shuffles across quads ----
        const f32x4 t0 = acc[0] * sf0;
        const f32x4 t1 = acc[1] * sf1;
        float mx = fmaxf(fmaxf(fmaxf(t0[0], t0[1]), fmaxf(t0[2], t0[3])),
                         fmaxf(fmaxf(t1[0], t1[1]), fmaxf(t1[2], t1[3])));
        mx = fmaxf(mx, __shfl_xor(mx, 16));
        mx = fmaxf(mx, __shfl_xor(mx, 32));
        const float mnew = fmaxf(mrow, mx);
        const float al = EXP2(mrow - mnew);
        mrow = mnew;
        f32x4 P0, P1;
        #pragma unroll
        for (int r = 0; r < 4; ++r) {
            P0[r] = EXP2(t0[r] - mnew);
            P1[r] = EXP2(t1[r] - mnew);
        }
        float rs = ((P0[0] + P0[1]) + (P0[2] + P0[3])) + ((P1[0] + P1[1]) + (P1[2] + P1[3]));
        rs += __shfl_xor(rs, 16);
        rs += __shfl_xor(rs, 32);
        lrow = lrow * al + rs;
        const f32x4 alv = {al, al, al, al};
        #pragma unroll
        for (int dt = 0; dt < 8; ++dt)
            Oacc[dt] *= alv;

        // P -> bf16 B-frags, fully in-register (no LDS round-trip)
        union { u32 w2[2]; s16x4 v; } B0, B1;
        B0.w2[0] = pack_rne(P0[0], P0[1]); B0.w2[1] = pack_rne(P0[2], P0[3]);
        B1.w2[0] = pack_rne(P1[0], P1[1]); B1.w2[1] = pack_rne(P1[2], P1[3]);

        // ---- P·V via two K=16 MFMAs per dt: Oacc = V^T(A) · P(B) = O^T ----
        const unsigned short* sVp = sVt[p];
        #pragma unroll
        for (int dt = 0; dt < 8; ++dt) {
            const char* vrow = (const char*)(sVp + (dt * 16 + lr) * 32);
            const s16x4 va0 = *(const s16x4*)(vrow + off0);
            const s16x4 va1 = *(const s16x4*)(vrow + off1);
            Oacc[dt] = MFMA16(va0, B0.v, Oacc[dt]);
            Oacc[dt] = MFMA16(va1, B1.v, Oacc[dt]);
        }

        if (more) { sf0 = nf0; sf1 = nf1; }
    }

    // ---- epilogue: O^T layout -> contiguous float4 stores per lane ----
    const float dpf = (float)DP[0];
    const float sc = dpf / lrow;
    const f32x4 scv = {sc, sc, sc, sc};
    float* orow = OUT + bh_off + (size_t)qrow * D_DIM + quad * 4;
    #pragma unroll
    for (int dt = 0; dt < 8; ++dt) {
        const f32x4 o = Oacc[dt] * scv;
        *(f32x4*)(orow + dt * 16) = o;
    }
}

extern "C" void kernel_launch(void* const* d_in, const int* in_sizes, int n_in,
                              void* d_out, int out_size, void* d_ws, size_t ws_size,
                              hipStream_t stream) {
    const float* q  = (const float*)d_in[0];
    const float* k  = (const float*)d_in[1];
    const float* v  = (const float*)d_in[2];
    const float* sf = (const float*)d_in[3];
    const int*   dp = (const int*)d_in[4];
    float* out = (float*)d_out;

    const size_t kc_ushorts = (size_t)32 * NITER * 32 * 256;
    unsigned short* Kc = (unsigned short*)d_ws;
    unsigned short* Vt = Kc + kc_ushorts;

    prep_k<<<4096, 256, 0, stream>>>(k, Kc);
    prep_v<<<1024, 256, 0, stream>>>(v, Vt);
    dim3 grid(S_LEN / BQ, 32);   // (32, 32) = 1024 blocks
    attn_fused<<<grid, dim3(256), 0, stream>>>(q, Kc, Vt, sf, dp, out);
}

// Round 2
// 336.509 us; speedup vs baseline: 1.2369x; 1.1784x over previous
//
#include <hip/hip_runtime.h>

#define S_LEN 2048
#define D_DIM 128
#define BQ 128
#define BK 32
#define NITER (S_LEN / BK)   // 64

typedef float f32x4 __attribute__((ext_vector_type(4)));
typedef short s16x8 __attribute__((ext_vector_type(8)));
typedef short s16x4 __attribute__((ext_vector_type(4)));
typedef unsigned int u32;

#if __has_builtin(__builtin_amdgcn_exp2f)
#define EXP2(x) __builtin_amdgcn_exp2f(x)
#else
#define EXP2(x) exp2f(x)
#endif

// pack two floats' bf16 into one u32: x0 in lower 16, x1 in upper 16
__device__ __forceinline__ u32 pack_trunc(float x0, float x1) {
    return __builtin_amdgcn_perm(__float_as_uint(x1), __float_as_uint(x0), 0x07060302u);
}
__device__ __forceinline__ u32 pack_rne(float x0, float x1) {
    return __builtin_amdgcn_perm(__float_as_uint(x1) + 0x8000u,
                                 __float_as_uint(x0) + 0x8000u, 0x07060302u);
}

#define GLOAD16(g, l) \
    __builtin_amdgcn_global_load_lds((const __attribute__((address_space(1))) u32*)(g), \
                                     (__attribute__((address_space(3))) u32*)(l), 16, 0, 0)

// K=16 bf16 MFMA: A/B frag = 4 bf16 (lane: elem k = quad*4 + j), C/D = f32x4.
#if __has_builtin(__builtin_amdgcn_mfma_f32_16x16x16bf16_1k)
__device__ __forceinline__ f32x4 MFMA16(s16x4 a, s16x4 b, f32x4 c) {
    return __builtin_amdgcn_mfma_f32_16x16x16bf16_1k(a, b, c, 0, 0, 0);
}
#else
__device__ __forceinline__ f32x4 MFMA16(s16x4 a, s16x4 b, f32x4 c) {
    asm("v_mfma_f32_16x16x16_bf16 %0, %1, %2, %0" : "+v"(c) : "v"(a), "v"(b));
    return c;
}
#endif

// ---------------- pre-pass: K -> hi/lo bf16, tiled + XOR-swizzled 16B units ----------------
// Kc layout: [bh][kt][r=0..31][u'=0..31][8 ushorts]; u = 2c (hi) / 2c+1 (lo); u' = u ^ (r&7).
__global__ void prep_k(const float* __restrict__ K, unsigned short* __restrict__ Kc) {
    const int t  = blockIdx.x * 256 + threadIdx.x;   // 2^20 threads
    const int c  = t & 15;
    const int s  = (t >> 4) & (S_LEN - 1);
    const int bh = t >> 15;
    const float* src = K + ((size_t)bh * S_LEN + s) * D_DIM + c * 8;
    const float4 a = *(const float4*)src;
    const float4 b = *(const float4*)(src + 4);
    const float x[8] = {a.x,a.y,a.z,a.w,b.x,b.y,b.z,b.w};
    u32 h[4], l[4];
    #pragma unroll
    for (int i = 0; i < 4; ++i) {
        const float x0 = x[2*i], x1 = x[2*i+1];
        h[i] = pack_trunc(x0, x1);
        const float r0 = x0 - __uint_as_float(__float_as_uint(x0) & 0xFFFF0000u);
        const float r1 = x1 - __uint_as_float(__float_as_uint(x1) & 0xFFFF0000u);
        l[i] = pack_trunc(r0, r1);
    }
    const int kt = s >> 5, r = s & 31, rl = r & 7;
    unsigned short* base = Kc + ((((size_t)bh * NITER + kt) * 32 + r) << 8);
    *(uint4*)(base + (((2*c)     ^ rl) << 3)) = make_uint4(h[0],h[1],h[2],h[3]);
    *(uint4*)(base + (((2*c + 1) ^ rl) << 3)) = make_uint4(l[0],l[1],l[2],l[3]);
}

// ---------------- pre-pass: V -> transposed bf16 tiles Vt[bh][kt][d][kk] ----------------
// 16B units within each 64B row XOR-swizzled: physical unit = logical ^ ((d>>1)&3).
__global__ void prep_v(const float* __restrict__ V, unsigned short* __restrict__ Vt) {
    const int t  = blockIdx.x * 256 + threadIdx.x;   // 2^18 threads
    const int d  = t & 127;
    const int kt = (t >> 7) & (NITER - 1);
    const int bh = t >> 13;
    const float* src = V + (((size_t)bh * NITER + kt) * BK) * D_DIM + d;
    u32 wv[16];
    #pragma unroll
    for (int i = 0; i < 16; ++i)
        wv[i] = pack_rne(src[(2*i) * D_DIM], src[(2*i+1) * D_DIM]);
    unsigned short* dst = Vt + ((((size_t)bh * NITER + kt) * D_DIM + d) << 5);
    const int vs = (d >> 1) & 3;
    #pragma unroll
    for (int i = 0; i < 4; ++i)
        *(uint4*)(dst + ((i ^ vs) << 3)) = make_uint4(wv[4*i],wv[4*i+1],wv[4*i+2],wv[4*i+3]);
}

// ---------------- hot kernel: 32 q-rows per wave, A-fragment (K, V^T) reuse ----------------
__global__ __launch_bounds__(256, 2)
void attn_fused(const float* __restrict__ Q, const unsigned short* __restrict__ Kc,
                const unsigned short* __restrict__ Vt, const float* __restrict__ SF,
                const int* __restrict__ DP, float* __restrict__ OUT)
{
    __shared__ __align__(16) unsigned short sK[2][32 * 256];    // 2 x 16 KB
    __shared__ __align__(16) unsigned short sVt[2][128 * 32];   // 2 x 8 KB

    const int bh   = blockIdx.y;
    const int q0   = blockIdx.x * BQ;
    const int tid  = threadIdx.x;
    const int w    = tid >> 6;
    const int lane = tid & 63;
    const int quad = lane >> 4;
    const int lr   = lane & 15;
    const int rl   = lr & 7;

    const size_t bh_off = (size_t)bh * S_LEN * D_DIM;
    const float LOG2E = 1.4426950408889634f;

    // ---- Q fragments for 2 q-groups, hi/lo bf16 split ----
    // lane holds Q[q = qrow[g]][d = d0*32 + quad*8 + j]
    s16x8 qhi[2][4], qlo[2][4];
    int qrow[2];
    #pragma unroll
    for (int g = 0; g < 2; ++g) {
        qrow[g] = q0 + w * 32 + g * 16 + lr;
        const float* qr = Q + bh_off + (size_t)qrow[g] * D_DIM + quad * 8;
        #pragma unroll
        for (int d0 = 0; d0 < 4; ++d0) {
            const float4 u0 = *(const float4*)(qr + d0 * 32);
            const float4 u1 = *(const float4*)(qr + d0 * 32 + 4);
            const float x[8] = {u0.x,u0.y,u0.z,u0.w,u1.x,u1.y,u1.z,u1.w};
            union { u32 w4[4]; s16x8 v; } H, L;
            #pragma unroll
            for (int i = 0; i < 4; ++i) {
                const float x0 = x[2*i], x1 = x[2*i+1];
                H.w4[i] = pack_trunc(x0, x1);
                const float r0 = x0 - __uint_as_float(__float_as_uint(x0) & 0xFFFF0000u);
                const float r1 = x1 - __uint_as_float(__float_as_uint(x1) & 0xFFFF0000u);
                L.w4[i] = pack_trunc(r0, r1);
            }
            qhi[g][d0] = H.v; qlo[g][d0] = L.v;
        }
    }

    // O^T accumulators: Oacc[g][dt][r] = O[q=qrow[g]][d = dt*16 + quad*4 + r]
    f32x4 Oacc[2][8] = {};
    float mrow[2] = {-INFINITY, -INFINITY};
    float lrow[2] = {0.f, 0.f};

    const unsigned short* KtBase = Kc + (((size_t)bh * NITER) << 13);
    const unsigned short* VtBase = Vt + (((size_t)bh * NITER) << 12);

    // lane-constant swizzled V read offsets (bytes within a 64B Vt row)
    const int vsl  = (lr >> 1) & 3;
    const int off0 = ((((quad >> 1))     ^ vsl) << 4) + (quad & 1) * 8;   // nt=0
    const int off1 = (((2 + (quad >> 1)) ^ vsl) << 4) + (quad & 1) * 8;   // nt=1

    // ---- prologue: DMA tile 0 -> buf 0; SF tile 0 -> regs ----
    #pragma unroll
    for (int i = 0; i < 4; ++i)
        GLOAD16(KtBase + (w * 4 + i) * 512 + lane * 8, &sK[0][(w * 4 + i) * 512]);
    #pragma unroll
    for (int i = 0; i < 2; ++i)
        GLOAD16(VtBase + (w * 2 + i) * 512 + lane * 8, &sVt[0][(w * 2 + i) * 512]);

    // SF: lane needs cols kt*32 + nt*16 + quad*4 + 0..3 of its q-row -> float4 loads
    const float* sfq[2];
    f32x4 sf0[2], sf1[2];
    {
        const f32x4 l2e = {LOG2E, LOG2E, LOG2E, LOG2E};
        #pragma unroll
        for (int g = 0; g < 2; ++g) {
            sfq[g] = SF + (size_t)qrow[g] * S_LEN + quad * 4;
            sf0[g] = *(const f32x4*)(sfq[g]) * l2e;
            sf1[g] = *(const f32x4*)(sfq[g] + 16) * l2e;
        }
    }

    for (int kt = 0; kt < NITER; ++kt) {
        const int p = kt & 1;
        // Publishes buf[p] (vmcnt(0) drain: its DMA was issued a full iteration
        // ago). Also guarantees everyone is done reading buf[1-p].
        __syncthreads();

        // ---- prefetch tile kt+1 into buf[1-p]; SF(kt+1) into regs ----
        f32x4 nf0[2], nf1[2];
        const bool more = (kt + 1 < NITER);
        if (more) {
            const unsigned short* Kn = KtBase + ((size_t)(kt + 1) << 13);
            const unsigned short* Vn = VtBase + ((size_t)(kt + 1) << 12);
            #pragma unroll
            for (int i = 0; i < 4; ++i)
                GLOAD16(Kn + (w * 4 + i) * 512 + lane * 8, &sK[1 - p][(w * 4 + i) * 512]);
            #pragma unroll
            for (int i = 0; i < 2; ++i)
                GLOAD16(Vn + (w * 2 + i) * 512 + lane * 8, &sVt[1 - p][(w * 2 + i) * 512]);
            const f32x4 l2e = {LOG2E, LOG2E, LOG2E, LOG2E};
            #pragma unroll
            for (int g = 0; g < 2; ++g) {
                nf0[g] = *(const f32x4*)(sfq[g] + (kt + 1) * 32) * l2e;
                nf1[g] = *(const f32x4*)(sfq[g] + (kt + 1) * 32 + 16) * l2e;
            }
        }

        // ---- QK^T, swapped operands; each K fragment reused by both q-groups ----
        // acc[g][nt][r] = S[q=qrow[g]][k = nt*16 + quad*4 + r]
        const unsigned short* sKp = sK[p];
        f32x4 acc[2][2] = {};
        #pragma unroll
        for (int nt = 0; nt < 2; ++nt) {
            const unsigned short* rowp = sKp + (nt * 16 + lr) * 256;
            #pragma unroll
            for (int d0 = 0; d0 < 4; ++d0) {
                const int uh = (8 * d0 + 2 * quad) ^ rl;
                const s16x8 kh8 = *(const s16x8*)(rowp + (uh << 3));
                const s16x8 kl8 = *(const s16x8*)(rowp + ((uh ^ 1) << 3));
                #pragma unroll
                for (int g = 0; g < 2; ++g) {
                    acc[g][nt] = __builtin_amdgcn_mfma_f32_16x16x32_bf16(kh8, qlo[g][d0], acc[g][nt], 0, 0, 0);
                    acc[g][nt] = __builtin_amdgcn_mfma_f32_16x16x32_bf16(kl8, qhi[g][d0], acc[g][nt], 0, 0, 0);
                    acc[g][nt] = __builtin_amdgcn_mfma_f32_16x16x32_bf16(kh8, qhi[g][d0], acc[g][nt], 0, 0, 0);
                }
            }
        }

        // ---- online softmax (base-2), lane-local rows + 2 shuffles per group ----
        union PB { u32 w2[2]; s16x4 v; } B0[2], B1[2];
        #pragma unroll
        for (int g = 0; g < 2; ++g) {
            const f32x4 t0 = acc[g][0] * sf0[g];
            const f32x4 t1 = acc[g][1] * sf1[g];
            float mx = fmaxf(fmaxf(fmaxf(t0[0], t0[1]), fmaxf(t0[2], t0[3])),
                             fmaxf(fmaxf(t1[0], t1[1]), fmaxf(t1[2], t1[3])));
            mx = fmaxf(mx, __shfl_xor(mx, 16));
            mx = fmaxf(mx, __shfl_xor(mx, 32));
            const float mnew = fmaxf(mrow[g], mx);
            const float al = EXP2(mrow[g] - mnew);
            mrow[g] = mnew;
            f32x4 P0, P1;
            #pragma unroll
            for (int r = 0; r < 4; ++r) {
                P0[r] = EXP2(t0[r] - mnew);
                P1[r] = EXP2(t1[r] - mnew);
            }
            float rs = ((P0[0] + P0[1]) + (P0[2] + P0[3])) + ((P1[0] + P1[1]) + (P1[2] + P1[3]));
            rs += __shfl_xor(rs, 16);
            rs += __shfl_xor(rs, 32);
            lrow[g] = lrow[g] * al + rs;
            const f32x4 alv = {al, al, al, al};
            #pragma unroll
            for (int dt = 0; dt < 8; ++dt)
                Oacc[g][dt] *= alv;
            B0[g].w2[0] = pack_rne(P0[0], P0[1]); B0[g].w2[1] = pack_rne(P0[2], P0[3]);
            B1[g].w2[0] = pack_rne(P1[0], P1[1]); B1[g].w2[1] = pack_rne(P1[2], P1[3]);
        }

        // ---- P·V; each V^T fragment reused by both q-groups ----
        const unsigned short* sVp = sVt[p];
        #pragma unroll
        for (int dt = 0; dt < 8; ++dt) {
            const char* vrow = (const char*)(sVp + (dt * 16 + lr) * 32);
            const s16x4 va0 = *(const s16x4*)(vrow + off0);
            const s16x4 va1 = *(const s16x4*)(vrow + off1);
            #pragma unroll
            for (int g = 0; g < 2; ++g) {
                Oacc[g][dt] = MFMA16(va0, B0[g].v, Oacc[g][dt]);
                Oacc[g][dt] = MFMA16(va1, B1[g].v, Oacc[g][dt]);
            }
        }

        if (more) {
            #pragma unroll
            for (int g = 0; g < 2; ++g) { sf0[g] = nf0[g]; sf1[g] = nf1[g]; }
        }
    }

    // ---- epilogue: O^T layout -> contiguous float4 stores per lane ----
    const float dpf = (float)DP[0];
    #pragma unroll
    for (int g = 0; g < 2; ++g) {
        const float sc = dpf / lrow[g];
        const f32x4 scv = {sc, sc, sc, sc};
        float* orow = OUT + bh_off + (size_t)qrow[g] * D_DIM + quad * 4;
        #pragma unroll
        for (int dt = 0; dt < 8; ++dt) {
            const f32x4 o = Oacc[g][dt] * scv;
            *(f32x4*)(orow + dt * 16) = o;
        }
    }
}

extern "C" void kernel_launch(void* const* d_in, const int* in_sizes, int n_in,
                              void* d_out, int out_size, void* d_ws, size_t ws_size,
                              hipStream_t stream) {
    const float* q  = (const float*)d_in[0];
    const float* k  = (const float*)d_in[1];
    const float* v  = (const float*)d_in[2];
    const float* sf = (const float*)d_in[3];
    const int*   dp = (const int*)d_in[4];
    float* out = (float*)d_out;

    const size_t kc_ushorts = (size_t)32 * NITER * 32 * 256;
    unsigned short* Kc = (unsigned short*)d_ws;
    unsigned short* Vt = Kc + kc_ushorts;

    prep_k<<<4096, 256, 0, stream>>>(k, Kc);
    prep_v<<<1024, 256, 0, stream>>>(v, Vt);
    dim3 grid(S_LEN / BQ, 32);   // (16, 32) = 512 blocks, exactly 2/CU at 48KB LDS
    attn_fused<<<grid, dim3(256), 0, stream>>>(q, Kc, Vt, sf, dp, out);
}

// Round 3
// 315.601 us; speedup vs baseline: 1.3189x; 1.0662x over previous
//
#include <hip/hip_runtime.h>

#define S_LEN 2048
#define D_DIM 128
#define BQ 128
#define BK 32
#define NITER (S_LEN / BK)   // 64

typedef float f32x4 __attribute__((ext_vector_type(4)));
typedef short s16x8 __attribute__((ext_vector_type(8)));
typedef short s16x4 __attribute__((ext_vector_type(4)));
typedef unsigned int u32;

#if __has_builtin(__builtin_amdgcn_exp2f)
#define EXP2(x) __builtin_amdgcn_exp2f(x)
#else
#define EXP2(x) exp2f(x)
#endif

// pack two floats' bf16 into one u32: x0 in lower 16, x1 in upper 16
__device__ __forceinline__ u32 pack_trunc(float x0, float x1) {
    return __builtin_amdgcn_perm(__float_as_uint(x1), __float_as_uint(x0), 0x07060302u);
}
__device__ __forceinline__ u32 pack_rne(float x0, float x1) {
    return __builtin_amdgcn_perm(__float_as_uint(x1) + 0x8000u,
                                 __float_as_uint(x0) + 0x8000u, 0x07060302u);
}

#define GLOAD16(g, l) \
    __builtin_amdgcn_global_load_lds((const __attribute__((address_space(1))) u32*)(g), \
                                     (__attribute__((address_space(3))) u32*)(l), 16, 0, 0)

// K=16 bf16 MFMA: A/B frag = 4 bf16 (lane: elem k = quad*4 + j), C/D = f32x4.
#if __has_builtin(__builtin_amdgcn_mfma_f32_16x16x16bf16_1k)
__device__ __forceinline__ f32x4 MFMA16(s16x4 a, s16x4 b, f32x4 c) {
    return __builtin_amdgcn_mfma_f32_16x16x16bf16_1k(a, b, c, 0, 0, 0);
}
#else
__device__ __forceinline__ f32x4 MFMA16(s16x4 a, s16x4 b, f32x4 c) {
    asm("v_mfma_f32_16x16x16_bf16 %0, %1, %2, %0" : "+v"(c) : "v"(a), "v"(b));
    return c;
}
#endif

// ---------------- pre-pass: K -> hi/lo bf16, tiled + XOR-swizzled 16B units ----------------
// Kc layout: [bh][kt][r=0..31][u'=0..31][8 ushorts]; u = 2c (hi) / 2c+1 (lo); u' = u ^ (r&7).
__global__ void prep_k(const float* __restrict__ K, unsigned short* __restrict__ Kc) {
    const int t  = blockIdx.x * 256 + threadIdx.x;   // 2^20 threads
    const int c  = t & 15;
    const int s  = (t >> 4) & (S_LEN - 1);
    const int bh = t >> 15;
    const float* src = K + ((size_t)bh * S_LEN + s) * D_DIM + c * 8;
    const float4 a = *(const float4*)src;
    const float4 b = *(const float4*)(src + 4);
    const float x[8] = {a.x,a.y,a.z,a.w,b.x,b.y,b.z,b.w};
    u32 h[4], l[4];
    #pragma unroll
    for (int i = 0; i < 4; ++i) {
        const float x0 = x[2*i], x1 = x[2*i+1];
        h[i] = pack_trunc(x0, x1);
        const float r0 = x0 - __uint_as_float(__float_as_uint(x0) & 0xFFFF0000u);
        const float r1 = x1 - __uint_as_float(__float_as_uint(x1) & 0xFFFF0000u);
        l[i] = pack_trunc(r0, r1);
    }
    const int kt = s >> 5, r = s & 31, rl = r & 7;
    unsigned short* base = Kc + ((((size_t)bh * NITER + kt) * 32 + r) << 8);
    *(uint4*)(base + (((2*c)     ^ rl) << 3)) = make_uint4(h[0],h[1],h[2],h[3]);
    *(uint4*)(base + (((2*c + 1) ^ rl) << 3)) = make_uint4(l[0],l[1],l[2],l[3]);
}

// ---------------- pre-pass: V -> transposed bf16 tiles Vt[bh][kt][d][kk] ----------------
// 16B units within each 64B row XOR-swizzled: physical unit = logical ^ ((d>>1)&3).
__global__ void prep_v(const float* __restrict__ V, unsigned short* __restrict__ Vt) {
    const int t  = blockIdx.x * 256 + threadIdx.x;   // 2^18 threads
    const int d  = t & 127;
    const int kt = (t >> 7) & (NITER - 1);
    const int bh = t >> 13;
    const float* src = V + (((size_t)bh * NITER + kt) * BK) * D_DIM + d;
    u32 wv[16];
    #pragma unroll
    for (int i = 0; i < 16; ++i)
        wv[i] = pack_rne(src[(2*i) * D_DIM], src[(2*i+1) * D_DIM]);
    unsigned short* dst = Vt + ((((size_t)bh * NITER + kt) * D_DIM + d) << 5);
    const int vs = (d >> 1) & 3;
    #pragma unroll
    for (int i = 0; i < 4; ++i)
        *(uint4*)(dst + ((i ^ vs) << 3)) = make_uint4(wv[4*i],wv[4*i+1],wv[4*i+2],wv[4*i+3]);
}

// ---------------- hot kernel: 32 q-rows per wave, defer-rescale + setprio ----------------
__global__ __launch_bounds__(256, 2)
void attn_fused(const float* __restrict__ Q, const unsigned short* __restrict__ Kc,
                const unsigned short* __restrict__ Vt, const float* __restrict__ SF,
                const int* __restrict__ DP, float* __restrict__ OUT)
{
    __shared__ __align__(16) unsigned short sK[2][32 * 256];    // 2 x 16 KB
    __shared__ __align__(16) unsigned short sVt[2][128 * 32];   // 2 x 8 KB

    const int bh   = blockIdx.y;
    const int q0   = blockIdx.x * BQ;
    const int tid  = threadIdx.x;
    const int w    = tid >> 6;
    const int lane = tid & 63;
    const int quad = lane >> 4;
    const int lr   = lane & 15;
    const int rl   = lr & 7;

    const size_t bh_off = (size_t)bh * S_LEN * D_DIM;
    const float LOG2E = 1.4426950408889634f;

    // ---- Q fragments for 2 q-groups, hi/lo bf16 split ----
    // lane holds Q[q = qrow[g]][d = d0*32 + quad*8 + j]
    s16x8 qhi[2][4], qlo[2][4];
    int qrow[2];
    #pragma unroll
    for (int g = 0; g < 2; ++g) {
        qrow[g] = q0 + w * 32 + g * 16 + lr;
        const float* qr = Q + bh_off + (size_t)qrow[g] * D_DIM + quad * 8;
        #pragma unroll
        for (int d0 = 0; d0 < 4; ++d0) {
            const float4 u0 = *(const float4*)(qr + d0 * 32);
            const float4 u1 = *(const float4*)(qr + d0 * 32 + 4);
            const float x[8] = {u0.x,u0.y,u0.z,u0.w,u1.x,u1.y,u1.z,u1.w};
            union { u32 w4[4]; s16x8 v; } H, L;
            #pragma unroll
            for (int i = 0; i < 4; ++i) {
                const float x0 = x[2*i], x1 = x[2*i+1];
                H.w4[i] = pack_trunc(x0, x1);
                const float r0 = x0 - __uint_as_float(__float_as_uint(x0) & 0xFFFF0000u);
                const float r1 = x1 - __uint_as_float(__float_as_uint(x1) & 0xFFFF0000u);
                L.w4[i] = pack_trunc(r0, r1);
            }
            qhi[g][d0] = H.v; qlo[g][d0] = L.v;
        }
    }

    // O^T accumulators: Oacc[g][dt][r] = O[q=qrow[g]][d = dt*16 + quad*4 + r]
    f32x4 Oacc[2][8] = {};
    float mrow[2] = {-INFINITY, -INFINITY};
    float lrow[2] = {0.f, 0.f};

    const unsigned short* KtBase = Kc + (((size_t)bh * NITER) << 13);
    const unsigned short* VtBase = Vt + (((size_t)bh * NITER) << 12);

    // lane-constant swizzled V read offsets (bytes within a 64B Vt row)
    const int vsl  = (lr >> 1) & 3;
    const int off0 = ((((quad >> 1))     ^ vsl) << 4) + (quad & 1) * 8;   // nt=0
    const int off1 = (((2 + (quad >> 1)) ^ vsl) << 4) + (quad & 1) * 8;   // nt=1

    // ---- prologue: DMA tile 0 -> buf 0; SF tile 0 -> regs ----
    #pragma unroll
    for (int i = 0; i < 4; ++i)
        GLOAD16(KtBase + (w * 4 + i) * 512 + lane * 8, &sK[0][(w * 4 + i) * 512]);
    #pragma unroll
    for (int i = 0; i < 2; ++i)
        GLOAD16(VtBase + (w * 2 + i) * 512 + lane * 8, &sVt[0][(w * 2 + i) * 512]);

    // SF: lane needs cols kt*32 + nt*16 + quad*4 + 0..3 of its q-row -> float4 loads
    const float* sfq[2];
    f32x4 sf0[2], sf1[2];
    {
        const f32x4 l2e = {LOG2E, LOG2E, LOG2E, LOG2E};
        #pragma unroll
        for (int g = 0; g < 2; ++g) {
            sfq[g] = SF + (size_t)qrow[g] * S_LEN + quad * 4;
            sf0[g] = *(const f32x4*)(sfq[g]) * l2e;
            sf1[g] = *(const f32x4*)(sfq[g] + 16) * l2e;
        }
    }

    for (int kt = 0; kt < NITER; ++kt) {
        const int p = kt & 1;
        // Publishes buf[p] (vmcnt(0) drain: its DMA was issued a full iteration
        // ago). Also guarantees everyone is done reading buf[1-p].
        __syncthreads();

        // ---- prefetch tile kt+1 into buf[1-p]; SF(kt+1) into regs ----
        f32x4 nf0[2], nf1[2];
        const bool more = (kt + 1 < NITER);
        if (more) {
            const unsigned short* Kn = KtBase + ((size_t)(kt + 1) << 13);
            const unsigned short* Vn = VtBase + ((size_t)(kt + 1) << 12);
            #pragma unroll
            for (int i = 0; i < 4; ++i)
                GLOAD16(Kn + (w * 4 + i) * 512 + lane * 8, &sK[1 - p][(w * 4 + i) * 512]);
            #pragma unroll
            for (int i = 0; i < 2; ++i)
                GLOAD16(Vn + (w * 2 + i) * 512 + lane * 8, &sVt[1 - p][(w * 2 + i) * 512]);
            const f32x4 l2e = {LOG2E, LOG2E, LOG2E, LOG2E};
            #pragma unroll
            for (int g = 0; g < 2; ++g) {
                nf0[g] = *(const f32x4*)(sfq[g] + (kt + 1) * 32) * l2e;
                nf1[g] = *(const f32x4*)(sfq[g] + (kt + 1) * 32 + 16) * l2e;
            }
        }

        // ---- QK^T, swapped operands; each K fragment reused by both q-groups ----
        // acc[g][nt][r] = S[q=qrow[g]][k = nt*16 + quad*4 + r]
        const unsigned short* sKp = sK[p];
        f32x4 acc[2][2] = {};
        __builtin_amdgcn_s_setprio(1);
        #pragma unroll
        for (int nt = 0; nt < 2; ++nt) {
            const unsigned short* rowp = sKp + (nt * 16 + lr) * 256;
            #pragma unroll
            for (int d0 = 0; d0 < 4; ++d0) {
                const int uh = (8 * d0 + 2 * quad) ^ rl;
                const s16x8 kh8 = *(const s16x8*)(rowp + (uh << 3));
                const s16x8 kl8 = *(const s16x8*)(rowp + ((uh ^ 1) << 3));
                #pragma unroll
                for (int g = 0; g < 2; ++g) {
                    acc[g][nt] = __builtin_amdgcn_mfma_f32_16x16x32_bf16(kh8, qlo[g][d0], acc[g][nt], 0, 0, 0);
                    acc[g][nt] = __builtin_amdgcn_mfma_f32_16x16x32_bf16(kl8, qhi[g][d0], acc[g][nt], 0, 0, 0);
                    acc[g][nt] = __builtin_amdgcn_mfma_f32_16x16x32_bf16(kh8, qhi[g][d0], acc[g][nt], 0, 0, 0);
                }
            }
        }
        __builtin_amdgcn_s_setprio(0);

        // ---- online softmax (base-2), lane-local rows + 2 shuffles per group ----
        // Defer-rescale: skip the O/l rescale when no row max grew (bit-exact:
        // al would be exp2(0) == 1). Wave-uniform branch via __all.
        union PB { u32 w2[2]; s16x4 v; } B0[2], B1[2];
        #pragma unroll
        for (int g = 0; g < 2; ++g) {
            const f32x4 t0 = acc[g][0] * sf0[g];
            const f32x4 t1 = acc[g][1] * sf1[g];
            float mx = fmaxf(fmaxf(fmaxf(t0[0], t0[1]), fmaxf(t0[2], t0[3])),
                             fmaxf(fmaxf(t1[0], t1[1]), fmaxf(t1[2], t1[3])));
            mx = fmaxf(mx, __shfl_xor(mx, 16));
            mx = fmaxf(mx, __shfl_xor(mx, 32));
            const float mnew = fmaxf(mrow[g], mx);
            if (!__all(mnew == mrow[g])) {
                const float al = EXP2(mrow[g] - mnew);
                mrow[g] = mnew;
                lrow[g] *= al;
                const f32x4 alv = {al, al, al, al};
                #pragma unroll
                for (int dt = 0; dt < 8; ++dt)
                    Oacc[g][dt] *= alv;
            }
            const float m = mrow[g];
            f32x4 P0, P1;
            #pragma unroll
            for (int r = 0; r < 4; ++r) {
                P0[r] = EXP2(t0[r] - m);
                P1[r] = EXP2(t1[r] - m);
            }
            float rs = ((P0[0] + P0[1]) + (P0[2] + P0[3])) + ((P1[0] + P1[1]) + (P1[2] + P1[3]));
            rs += __shfl_xor(rs, 16);
            rs += __shfl_xor(rs, 32);
            lrow[g] += rs;
            B0[g].w2[0] = pack_rne(P0[0], P0[1]); B0[g].w2[1] = pack_rne(P0[2], P0[3]);
            B1[g].w2[0] = pack_rne(P1[0], P1[1]); B1[g].w2[1] = pack_rne(P1[2], P1[3]);
        }

        // ---- P·V; each V^T fragment reused by both q-groups ----
        const unsigned short* sVp = sVt[p];
        __builtin_amdgcn_s_setprio(1);
        #pragma unroll
        for (int dt = 0; dt < 8; ++dt) {
            const char* vrow = (const char*)(sVp + (dt * 16 + lr) * 32);
            const s16x4 va0 = *(const s16x4*)(vrow + off0);
            const s16x4 va1 = *(const s16x4*)(vrow + off1);
            #pragma unroll
            for (int g = 0; g < 2; ++g) {
                Oacc[g][dt] = MFMA16(va0, B0[g].v, Oacc[g][dt]);
                Oacc[g][dt] = MFMA16(va1, B1[g].v, Oacc[g][dt]);
            }
        }
        __builtin_amdgcn_s_setprio(0);

        if (more) {
            #pragma unroll
            for (int g = 0; g < 2; ++g) { sf0[g] = nf0[g]; sf1[g] = nf1[g]; }
        }
    }

    // ---- epilogue: O^T layout -> contiguous float4 stores per lane ----
    const float dpf = (float)DP[0];
    #pragma unroll
    for (int g = 0; g < 2; ++g) {
        const float sc = dpf / lrow[g];
        const f32x4 scv = {sc, sc, sc, sc};
        float* orow = OUT + bh_off + (size_t)qrow[g] * D_DIM + quad * 4;
        #pragma unroll
        for (int dt = 0; dt < 8; ++dt) {
            const f32x4 o = Oacc[g][dt] * scv;
            *(f32x4*)(orow + dt * 16) = o;
        }
    }
}

extern "C" void kernel_launch(void* const* d_in, const int* in_sizes, int n_in,
                              void* d_out, int out_size, void* d_ws, size_t ws_size,
                              hipStream_t stream) {
    const float* q  = (const float*)d_in[0];
    const float* k  = (const float*)d_in[1];
    const float* v  = (const float*)d_in[2];
    const float* sf = (const float*)d_in[3];
    const int*   dp = (const int*)d_in[4];
    float* out = (float*)d_out;

    const size_t kc_ushorts = (size_t)32 * NITER * 32 * 256;
    unsigned short* Kc = (unsigned short*)d_ws;
    unsigned short* Vt = Kc + kc_ushorts;

    prep_k<<<4096, 256, 0, stream>>>(k, Kc);
    prep_v<<<1024, 256, 0, stream>>>(v, Vt);
    dim3 grid(S_LEN / BQ, 32);   // (16, 32) = 512 blocks, exactly 2/CU at 48KB LDS
    attn_fused<<<grid, dim3(256), 0, stream>>>(q, Kc, Vt, sf, dp, out);
}

// Round 4
// 312.255 us; speedup vs baseline: 1.3330x; 1.0107x over previous
//
#include <hip/hip_runtime.h>

#define S_LEN 2048
#define D_DIM 128
#define BQ 128
#define BK 32
#define NITER (S_LEN / BK)   // 64

typedef float f32x4 __attribute__((ext_vector_type(4)));
typedef short s16x8 __attribute__((ext_vector_type(8)));
typedef short s16x4 __attribute__((ext_vector_type(4)));
typedef unsigned int u32;

#if __has_builtin(__builtin_amdgcn_exp2f)
#define EXP2(x) __builtin_amdgcn_exp2f(x)
#else
#define EXP2(x) exp2f(x)
#endif

// pack two floats' bf16 into one u32: x0 in lower 16, x1 in upper 16
__device__ __forceinline__ u32 pack_trunc(float x0, float x1) {
    return __builtin_amdgcn_perm(__float_as_uint(x1), __float_as_uint(x0), 0x07060302u);
}
__device__ __forceinline__ u32 pack_rne(float x0, float x1) {
    return __builtin_amdgcn_perm(__float_as_uint(x1) + 0x8000u,
                                 __float_as_uint(x0) + 0x8000u, 0x07060302u);
}

#define GLOAD16(g, l) \
    __builtin_amdgcn_global_load_lds((const __attribute__((address_space(1))) u32*)(g), \
                                     (__attribute__((address_space(3))) u32*)(l), 16, 0, 0)

// K=16 bf16 MFMA: A/B frag = 4 bf16 (lane: elem k = quad*4 + j), C/D = f32x4.
#if __has_builtin(__builtin_amdgcn_mfma_f32_16x16x16bf16_1k)
__device__ __forceinline__ f32x4 MFMA16(s16x4 a, s16x4 b, f32x4 c) {
    return __builtin_amdgcn_mfma_f32_16x16x16bf16_1k(a, b, c, 0, 0, 0);
}
#else
__device__ __forceinline__ f32x4 MFMA16(s16x4 a, s16x4 b, f32x4 c) {
    asm("v_mfma_f32_16x16x16_bf16 %0, %1, %2, %0" : "+v"(c) : "v"(a), "v"(b));
    return c;
}
#endif

// ---- butterfly over lanes {l, l^16, l^32, l^48} on the VALU pipe (gfx950 permlane swaps).
// Both outputs of a self-swap cover {own, partner} per lane -> op(out0,out1) = op(x[l], x[l^16/32]).
// Bit-identical to the __shfl_xor tree (fp add/max are commutative).
#if __has_builtin(__builtin_amdgcn_permlane16_swap) && __has_builtin(__builtin_amdgcn_permlane32_swap)
#define BFLY(x, OP)                                                                       \
    {                                                                                     \
        auto p_ = __builtin_amdgcn_permlane16_swap(__float_as_uint(x), __float_as_uint(x), false, false); \
        x = OP(__uint_as_float(p_[0]), __uint_as_float(p_[1]));                           \
        auto q_ = __builtin_amdgcn_permlane32_swap(__float_as_uint(x), __float_as_uint(x), false, false); \
        x = OP(__uint_as_float(q_[0]), __uint_as_float(q_[1]));                           \
    }
#else
#define BFLY(x, OP)                      \
    {                                    \
        x = OP(x, __shfl_xor(x, 16));    \
        x = OP(x, __shfl_xor(x, 32));    \
    }
#endif
__device__ __forceinline__ float fadd_(float a, float b) { return a + b; }

// ---------------- pre-pass: K -> hi/lo bf16, tiled + XOR-swizzled 16B units ----------------
// Kc layout: [bh][kt][r=0..31][u'=0..31][8 ushorts]; u = 2c (hi) / 2c+1 (lo); u' = u ^ (r&7).
__global__ void prep_k(const float* __restrict__ K, unsigned short* __restrict__ Kc) {
    const int t  = blockIdx.x * 256 + threadIdx.x;   // 2^20 threads
    const int c  = t & 15;
    const int s  = (t >> 4) & (S_LEN - 1);
    const int bh = t >> 15;
    const float* src = K + ((size_t)bh * S_LEN + s) * D_DIM + c * 8;
    const float4 a = *(const float4*)src;
    const float4 b = *(const float4*)(src + 4);
    const float x[8] = {a.x,a.y,a.z,a.w,b.x,b.y,b.z,b.w};
    u32 h[4], l[4];
    #pragma unroll
    for (int i = 0; i < 4; ++i) {
        const float x0 = x[2*i], x1 = x[2*i+1];
        h[i] = pack_trunc(x0, x1);
        const float r0 = x0 - __uint_as_float(__float_as_uint(x0) & 0xFFFF0000u);
        const float r1 = x1 - __uint_as_float(__float_as_uint(x1) & 0xFFFF0000u);
        l[i] = pack_trunc(r0, r1);
    }
    const int kt = s >> 5, r = s & 31, rl = r & 7;
    unsigned short* base = Kc + ((((size_t)bh * NITER + kt) * 32 + r) << 8);
    *(uint4*)(base + (((2*c)     ^ rl) << 3)) = make_uint4(h[0],h[1],h[2],h[3]);
    *(uint4*)(base + (((2*c + 1) ^ rl) << 3)) = make_uint4(l[0],l[1],l[2],l[3]);
}

// ---------------- pre-pass: V -> per-lane PV fragment chunks ----------------
// Vt[bh][kt][dt(8)][lane(64)][8 ushorts]: for lane = quad*16+lr,
//   elems 0..3 = bf16(V[kt*32 +    quad*4 + j][dt*16 + lr])  (va0)
//   elems 4..7 = bf16(V[kt*32 + 16 + quad*4 + j][dt*16 + lr])  (va1)
// The hot kernel loads one dwordx4 per (dt) per lane -> coalesced 1KB per instruction.
__global__ void prep_v(const float* __restrict__ V, unsigned short* __restrict__ Vt) {
    const int t  = blockIdx.x * 256 + threadIdx.x;   // 2^18 threads: (bh, kt, d)
    const int d  = t & 127;
    const int kt = (t >> 7) & (NITER - 1);
    const int bh = t >> 13;
    const float* src = V + (((size_t)bh * NITER + kt) * BK) * D_DIM + d;
    const int dt = d >> 4, lr = d & 15;
    unsigned short* base = Vt + ((((size_t)bh * NITER + kt) * 8 + dt) << 9);
    #pragma unroll
    for (int q = 0; q < 4; ++q) {
        u32 w0 = pack_rne(src[(q*4+0) * D_DIM],    src[(q*4+1) * D_DIM]);
        u32 w1 = pack_rne(src[(q*4+2) * D_DIM],    src[(q*4+3) * D_DIM]);
        u32 w2 = pack_rne(src[(16+q*4+0) * D_DIM], src[(16+q*4+1) * D_DIM]);
        u32 w3 = pack_rne(src[(16+q*4+2) * D_DIM], src[(16+q*4+3) * D_DIM]);
        *(uint4*)(base + ((q * 16 + lr) << 3)) = make_uint4(w0, w1, w2, w3);
    }
}

// ---------------- hot kernel: 32 q-rows per wave, V in registers, VALU butterflies ----------------
__global__ __launch_bounds__(256, 2)
void attn_fused(const float* __restrict__ Q, const unsigned short* __restrict__ Kc,
                const unsigned short* __restrict__ Vt, const float* __restrict__ SF,
                const int* __restrict__ DP, float* __restrict__ OUT)
{
    __shared__ __align__(16) unsigned short sK[2][32 * 256];    // 2 x 16 KB (K only)

    const int bh   = blockIdx.y;
    const int q0   = blockIdx.x * BQ;
    const int tid  = threadIdx.x;
    const int w    = tid >> 6;
    const int lane = tid & 63;
    const int quad = lane >> 4;
    const int lr   = lane & 15;
    const int rl   = lr & 7;

    const size_t bh_off = (size_t)bh * S_LEN * D_DIM;
    const float LOG2E = 1.4426950408889634f;

    // ---- Q fragments for 2 q-groups, hi/lo bf16 split ----
    // lane holds Q[q = qrow[g]][d = d0*32 + quad*8 + j]
    s16x8 qhi[2][4], qlo[2][4];
    int qrow[2];
    #pragma unroll
    for (int g = 0; g < 2; ++g) {
        qrow[g] = q0 + w * 32 + g * 16 + lr;
        const float* qr = Q + bh_off + (size_t)qrow[g] * D_DIM + quad * 8;
        #pragma unroll
        for (int d0 = 0; d0 < 4; ++d0) {
            const float4 u0 = *(const float4*)(qr + d0 * 32);
            const float4 u1 = *(const float4*)(qr + d0 * 32 + 4);
            const float x[8] = {u0.x,u0.y,u0.z,u0.w,u1.x,u1.y,u1.z,u1.w};
            union { u32 w4[4]; s16x8 v; } H, L;
            #pragma unroll
            for (int i = 0; i < 4; ++i) {
                const float x0 = x[2*i], x1 = x[2*i+1];
                H.w4[i] = pack_trunc(x0, x1);
                const float r0 = x0 - __uint_as_float(__float_as_uint(x0) & 0xFFFF0000u);
                const float r1 = x1 - __uint_as_float(__float_as_uint(x1) & 0xFFFF0000u);
                L.w4[i] = pack_trunc(r0, r1);
            }
            qhi[g][d0] = H.v; qlo[g][d0] = L.v;
        }
    }

    // O^T accumulators: Oacc[g][dt][r] = O[q=qrow[g]][d = dt*16 + quad*4 + r]
    f32x4 Oacc[2][8] = {};
    float mrow[2] = {-INFINITY, -INFINITY};
    float lrow[2] = {0.f, 0.f};

    const unsigned short* KtBase = Kc + (((size_t)bh * NITER) << 13);
    const unsigned short* VtBase = Vt + (((size_t)bh * NITER) << 12) + (lane << 3);

    // ---- prologue: DMA K tile 0 -> buf 0; SF tile 0 -> regs ----
    #pragma unroll
    for (int i = 0; i < 4; ++i)
        GLOAD16(KtBase + (w * 4 + i) * 512 + lane * 8, &sK[0][(w * 4 + i) * 512]);

    // SF: lane needs cols kt*32 + nt*16 + quad*4 + 0..3 of its q-row -> float4 loads
    const float* sfq[2];
    f32x4 sf0[2], sf1[2];
    {
        const f32x4 l2e = {LOG2E, LOG2E, LOG2E, LOG2E};
        #pragma unroll
        for (int g = 0; g < 2; ++g) {
            sfq[g] = SF + (size_t)qrow[g] * S_LEN + quad * 4;
            sf0[g] = *(const f32x4*)(sfq[g]) * l2e;
            sf1[g] = *(const f32x4*)(sfq[g] + 16) * l2e;
        }
    }

    for (int kt = 0; kt < NITER; ++kt) {
        const int p = kt & 1;
        // Publishes sK[p] (vmcnt(0) drain: its DMA was issued a full iteration
        // ago). Also guarantees everyone is done reading sK[1-p].
        __syncthreads();

        // ---- V(kt) -> registers, issued FIRST so the pre-PV vmcnt wait does not
        // drain the K DMAs issued below. Consumed ~QK+softmax later (latency covered).
        uint4 vreg[8];
        {
            const unsigned short* Vk = VtBase + ((size_t)kt << 12);
            #pragma unroll
            for (int dt = 0; dt < 8; ++dt)
                vreg[dt] = *(const uint4*)(Vk + (dt << 9));
        }

        // ---- prefetch K tile kt+1 into buf[1-p]; SF(kt+1) into regs ----
        f32x4 nf0[2], nf1[2];
        const bool more = (kt + 1 < NITER);
        if (more) {
            const unsigned short* Kn = KtBase + ((size_t)(kt + 1) << 13);
            #pragma unroll
            for (int i = 0; i < 4; ++i)
                GLOAD16(Kn + (w * 4 + i) * 512 + lane * 8, &sK[1 - p][(w * 4 + i) * 512]);
            const f32x4 l2e = {LOG2E, LOG2E, LOG2E, LOG2E};
            #pragma unroll
            for (int g = 0; g < 2; ++g) {
                nf0[g] = *(const f32x4*)(sfq[g] + (kt + 1) * 32) * l2e;
                nf1[g] = *(const f32x4*)(sfq[g] + (kt + 1) * 32 + 16) * l2e;
            }
        }

        // ---- QK^T, swapped operands; each K fragment reused by both q-groups ----
        // acc[g][nt][r] = S[q=qrow[g]][k = nt*16 + quad*4 + r]
        const unsigned short* sKp = sK[p];
        f32x4 acc[2][2] = {};
        __builtin_amdgcn_s_setprio(1);
        #pragma unroll
        for (int nt = 0; nt < 2; ++nt) {
            const unsigned short* rowp = sKp + (nt * 16 + lr) * 256;
            #pragma unroll
            for (int d0 = 0; d0 < 4; ++d0) {
                const int uh = (8 * d0 + 2 * quad) ^ rl;
                const s16x8 kh8 = *(const s16x8*)(rowp + (uh << 3));
                const s16x8 kl8 = *(const s16x8*)(rowp + ((uh ^ 1) << 3));
                #pragma unroll
                for (int g = 0; g < 2; ++g) {
                    acc[g][nt] = __builtin_amdgcn_mfma_f32_16x16x32_bf16(kh8, qlo[g][d0], acc[g][nt], 0, 0, 0);
                    acc[g][nt] = __builtin_amdgcn_mfma_f32_16x16x32_bf16(kl8, qhi[g][d0], acc[g][nt], 0, 0, 0);
                    acc[g][nt] = __builtin_amdgcn_mfma_f32_16x16x32_bf16(kh8, qhi[g][d0], acc[g][nt], 0, 0, 0);
                }
            }
        }
        __builtin_amdgcn_s_setprio(0);

        // ---- online softmax (base-2), lane-local rows + VALU butterflies ----
        // Defer-rescale: skip the O/l rescale when no row max grew (bit-exact:
        // al would be exp2(0) == 1). Wave-uniform branch via __all.
        union PB { u32 w2[2]; s16x4 v; } B0[2], B1[2];
        #pragma unroll
        for (int g = 0; g < 2; ++g) {
            const f32x4 t0 = acc[g][0] * sf0[g];
            const f32x4 t1 = acc[g][1] * sf1[g];
            float mx = fmaxf(fmaxf(fmaxf(t0[0], t0[1]), fmaxf(t0[2], t0[3])),
                             fmaxf(fmaxf(t1[0], t1[1]), fmaxf(t1[2], t1[3])));
            BFLY(mx, fmaxf);
            const float mnew = fmaxf(mrow[g], mx);
            if (!__all(mnew == mrow[g])) {
                const float al = EXP2(mrow[g] - mnew);
                mrow[g] = mnew;
                lrow[g] *= al;
                const f32x4 alv = {al, al, al, al};
                #pragma unroll
                for (int dt = 0; dt < 8; ++dt)
                    Oacc[g][dt] *= alv;
            }
            const float m = mrow[g];
            f32x4 P0, P1;
            #pragma unroll
            for (int r = 0; r < 4; ++r) {
                P0[r] = EXP2(t0[r] - m);
                P1[r] = EXP2(t1[r] - m);
            }
            float rs = ((P0[0] + P0[1]) + (P0[2] + P0[3])) + ((P1[0] + P1[1]) + (P1[2] + P1[3]));
            BFLY(rs, fadd_);
            lrow[g] += rs;
            B0[g].w2[0] = pack_rne(P0[0], P0[1]); B0[g].w2[1] = pack_rne(P0[2], P0[3]);
            B1[g].w2[0] = pack_rne(P1[0], P1[1]); B1[g].w2[1] = pack_rne(P1[2], P1[3]);
        }

        // ---- P·V from registers; each V fragment reused by both q-groups ----
        __builtin_amdgcn_s_setprio(1);
        #pragma unroll
        for (int dt = 0; dt < 8; ++dt) {
            union { uint4 u; struct { s16x4 a0; s16x4 a1; } s; } vv;
            vv.u = vreg[dt];
            #pragma unroll
            for (int g = 0; g < 2; ++g) {
                Oacc[g][dt] = MFMA16(vv.s.a0, B0[g].v, Oacc[g][dt]);
                Oacc[g][dt] = MFMA16(vv.s.a1, B1[g].v, Oacc[g][dt]);
            }
        }
        __builtin_amdgcn_s_setprio(0);

        if (more) {
            #pragma unroll
            for (int g = 0; g < 2; ++g) { sf0[g] = nf0[g]; sf1[g] = nf1[g]; }
        }
    }

    // ---- epilogue: O^T layout -> contiguous float4 stores per lane ----
    const float dpf = (float)DP[0];
    #pragma unroll
    for (int g = 0; g < 2; ++g) {
        const float sc = dpf / lrow[g];
        const f32x4 scv = {sc, sc, sc, sc};
        float* orow = OUT + bh_off + (size_t)qrow[g] * D_DIM + quad * 4;
        #pragma unroll
        for (int dt = 0; dt < 8; ++dt) {
            const f32x4 o = Oacc[g][dt] * scv;
            *(f32x4*)(orow + dt * 16) = o;
        }
    }
}

extern "C" void kernel_launch(void* const* d_in, const int* in_sizes, int n_in,
                              void* d_out, int out_size, void* d_ws, size_t ws_size,
                              hipStream_t stream) {
    const float* q  = (const float*)d_in[0];
    const float* k  = (const float*)d_in[1];
    const float* v  = (const float*)d_in[2];
    const float* sf = (const float*)d_in[3];
    const int*   dp = (const int*)d_in[4];
    float* out = (float*)d_out;

    const size_t kc_ushorts = (size_t)32 * NITER * 32 * 256;
    unsigned short* Kc = (unsigned short*)d_ws;
    unsigned short* Vt = Kc + kc_ushorts;

    prep_k<<<4096, 256, 0, stream>>>(k, Kc);
    prep_v<<<1024, 256, 0, stream>>>(v, Vt);
    dim3 grid(S_LEN / BQ, 32);   // (16, 32) = 512 blocks, 2/CU
    attn_fused<<<grid, dim3(256), 0, stream>>>(q, Kc, Vt, sf, dp, out);
}